// Round 9
// baseline (87.010 us; speedup 1.0000x reference)
//
#include <hip/hip_runtime.h>

#define NROWS 8192
#define KDIM  512
#define NT    64                 // 8192/128 tiles per dim
#define NBLK  (NT*(NT+1)/2)      // upper-triangle tile pairs = 2080
#define SCL1  0x7F7F7F7F         // E8M0 scale bytes = 2^0 = 1.0
#define STRIP4 8192              // 32 rows x 512 k x 0.5 B per strip
#define C2    0.0144269504f      // log2(e)/100

typedef __attribute__((ext_vector_type(16))) float f32x16;
typedef __attribute__((ext_vector_type(4))) int i32x4;
typedef __attribute__((ext_vector_type(8))) int i32x8;

// async global->LDS, 16B per lane; global src is per-lane, LDS dest is
// wave-uniform base + lane*16 (HW rule; pattern validated correct in round 1)
#define GLDS(g, l) __builtin_amdgcn_global_load_lds( \
    (const __attribute__((address_space(1))) void*)(g), \
    (__attribute__((address_space(3))) void*)(l), 16, 0, 0)

__device__ __forceinline__ i32x8 mk_op4(i32x4 lo) {
    i32x8 r;
    r[0] = lo[0]; r[1] = lo[1]; r[2] = lo[2]; r[3] = lo[3];
    r[4] = 0; r[5] = 0; r[6] = 0; r[7] = 0;   // fp4 uses only first 4 dwords
    return r;
}

// nearest e2m1 (scale 1.0) code for |x|: {0,0.5,1,1.5,2,3,4,6}
__device__ __forceinline__ int fp4_code(float x) {
    float v = fabsf(x);
    int c = v < 0.25f ? 0 : v < 0.75f ? 1 : v < 1.25f ? 2 : v < 1.75f ? 3
          : v < 2.5f  ? 4 : v < 3.5f  ? 5 : v < 5.0f  ? 6 : 7;
    return c | (x < 0.f ? 8 : 0);
}

// z (fp32) -> fp4 e2m1 in MFMA-operand order (bitwise identical zb4/nq to all
// prior rounds). nq[i] = -log2e/100 * ||z_i||^2 (exact fp32).
__global__ __launch_bounds__(256) void prep_kernel(const float* __restrict__ z,
                                                   unsigned char* __restrict__ zb4,
                                                   float* __restrict__ nq) {
    int wave = threadIdx.x >> 6, lane = threadIdx.x & 63;
    int row = blockIdx.x * 4 + wave;
    const float* zr = z + (size_t)row * KDIM + lane * 8;
    float4 v0 = *(const float4*)zr;
    float4 v1 = *(const float4*)(zr + 4);
    float vals[8] = {v0.x, v0.y, v0.z, v0.w, v1.x, v1.y, v1.z, v1.w};
    float s = 0.f;
    unsigned int pk = 0u;
#pragma unroll
    for (int i = 0; i < 8; ++i) {
        s += vals[i] * vals[i];
        pk |= (unsigned int)fp4_code(vals[i]) << (4 * i);   // nibble i = k0+i
    }
    int strip = row >> 5, lr = row & 31;
    size_t addr = (size_t)strip * STRIP4 + (lane >> 3) * 1024 +
                  ((lane >> 2) & 1) * 512 + lr * 16 + (lane & 3) * 4;
    *(unsigned int*)(zb4 + addr) = pk;
#pragma unroll
    for (int off = 32; off; off >>= 1) s += __shfl_down(s, off);
    if (lane == 0) nq[row] = -C2 * s;
}

// 128x128 Gram tile per block, 64x64 per wave (2x2 32x32x64 MX-fp4 MFMA).
// NEW: slice-granular double-buffered LDS staging. Theory: rounds 5-8 proved
// the bottleneck is NOT L2 latency (load batching null) nor L2 BW (traffic
// cut null) nor occupancy (null) — it is the per-CU L1/TA path: ~16.6K
// all-miss cache lines per CU at ~4cy/line ~= 27 us, matching gram's ~30.
// LDS staging fetches each line ONCE per block (waves share; TA lines/CU
// halved) and converts 64 of 128 per-wave operand reads into ds_read_b128
// (LDS pipe, not TA). Unlike round 1's failed version: 8 KB slices (not a
// 64 KB monolith), one __syncthreads per slice (its built-in vmcnt(0) is
// exactly the "slice t arrived" wait), 16 KB LDS -> 3 blocks/CU, and NO
// atomics (rounds 1-4: any per-block agent-scope fence costs >= 15 us).
// Byte-copy staging + same rotated slice order -> bitwise-identical result.
__global__ __launch_bounds__(256, 3) void gram_kernel(const unsigned char* __restrict__ zb4,
                                                      const float* __restrict__ nq,
                                                      float* __restrict__ part) {
    __shared__ unsigned char lds[2][8192];   // [buf][A:4KB | B:4KB]
    __shared__ float wsum[4];

    int tid = threadIdx.x;
    int wave = tid >> 6, lane = tid & 63;
    int ln31 = lane & 31, kh = lane >> 5;
    int wm = wave >> 1, wn = wave & 1;

    // linear block id -> (bi, bj), bi <= bj : closed form + fixup (round 5)
    int x = blockIdx.x;
    float sqv = __builtin_sqrtf(16641.0f - 8.0f * (float)x);   // (2*NT+1)^2
    int bi = (int)((129.0f - sqv) * 0.5f);
    while ((bi + 1) * NT - ((bi + 1) * bi >> 1) <= x) ++bi;
    while (bi * NT - (bi * (bi - 1) >> 1) > x) --bi;
    int rem = x - (bi * NT - (bi * (bi - 1) >> 1));
    int bj = bi + rem;
    int rot = blockIdx.x & 7;

    // staging: wave w copies strip w of A and strip w of B (1 KB each/slice)
    const unsigned char* sA = zb4 + (size_t)(bi * 4 + wave) * STRIP4 + lane * 16;
    const unsigned char* sB = zb4 + (size_t)(bj * 4 + wave) * STRIP4 + lane * 16;

    // ---- prefetch epilogue nq operands (independent of k-loop, round 5) ----
    int rowBase = bi * 128 + wm * 64;
    int colBase = bj * 128 + wn * 64;
    float nqj[2] = { nq[colBase + ln31], nq[colBase + 32 + ln31] };
    float4 nq4[2][4];
#pragma unroll
    for (int mi = 0; mi < 2; ++mi)
#pragma unroll
        for (int g = 0; g < 4; ++g)
            nq4[mi][g] = *(const float4*)(nq + rowBase + mi * 32 + 4 * kh + 8 * g);

    // prologue: stage slice 0 into buf 0
    {
        int off = (rot & 7) * 1024;
        GLDS(sA + off, &lds[0][wave * 1024]);
        GLDS(sB + off, &lds[0][4096 + wave * 1024]);
    }

    f32x16 accf[2][2];
#pragma unroll
    for (int mi = 0; mi < 2; ++mi)
#pragma unroll
        for (int ni = 0; ni < 2; ++ni)
#pragma unroll
            for (int r = 0; r < 16; ++r) accf[mi][ni][r] = 0.f;

    // per-wave LDS read offsets (same byte layout as the global strips)
    int rdA0 = (wm * 2) * 1024 + kh * 512 + ln31 * 16;
    int rdB0 = 4096 + (wn * 2) * 1024 + kh * 512 + ln31 * 16;

#pragma unroll
    for (int t = 0; t < 8; ++t) {
        // __syncthreads emits s_waitcnt vmcnt(0) lgkmcnt(0) + s_barrier:
        // = "slice t arrived everywhere AND everyone done reading buf[t-1]"
        __syncthreads();
        if (t < 7) {   // stage slice t+1 into the other buffer (overlaps compute)
            int off = ((t + 1 + rot) & 7) * 1024;
            unsigned char* dst = &lds[(t + 1) & 1][0];
            GLDS(sA + off, dst + wave * 1024);
            GLDS(sB + off, dst + 4096 + wave * 1024);
        }
        const unsigned char* buf = &lds[t & 1][0];
        i32x8 a0 = mk_op4(*(const i32x4*)(buf + rdA0));
        i32x8 a1 = mk_op4(*(const i32x4*)(buf + rdA0 + 1024));
        i32x8 b0 = mk_op4(*(const i32x4*)(buf + rdB0));
        i32x8 b1 = mk_op4(*(const i32x4*)(buf + rdB0 + 1024));
        // cbsz=4 (A=fp4), blgp=4 (B=fp4), scales = 1.0
        accf[0][0] = __builtin_amdgcn_mfma_scale_f32_32x32x64_f8f6f4(a0, b0, accf[0][0], 4, 4, 0, SCL1, 0, SCL1);
        accf[0][1] = __builtin_amdgcn_mfma_scale_f32_32x32x64_f8f6f4(a0, b1, accf[0][1], 4, 4, 0, SCL1, 0, SCL1);
        accf[1][0] = __builtin_amdgcn_mfma_scale_f32_32x32x64_f8f6f4(a1, b0, accf[1][0], 4, 4, 0, SCL1, 0, SCL1);
        accf[1][1] = __builtin_amdgcn_mfma_scale_f32_32x32x64_f8f6f4(a1, b1, accf[1][1], 4, 4, 0, SCL1, 0, SCL1);
    }

    // ---- fused epilogue: exp2( min( s*2C2 + nq_i + nq_j, 0 ) ) ----
    float local = 0.f;
    if (bi != bj) {
#pragma unroll
        for (int mi = 0; mi < 2; ++mi) {
#pragma unroll
            for (int reg = 0; reg < 16; ++reg) {
                float nqi = ((const float*)&nq4[mi][reg >> 2])[reg & 3];
#pragma unroll
                for (int ni = 0; ni < 2; ++ni) {
                    float arg = fmaf(accf[mi][ni][reg], 2.f * C2, nqi + nqj[ni]);
                    local += __builtin_exp2f(fminf(arg, 0.f));
                }
            }
        }
    } else {
#pragma unroll
        for (int mi = 0; mi < 2; ++mi) {
#pragma unroll
            for (int reg = 0; reg < 16; ++reg) {
                int rowf = (reg & 3) + 8 * (reg >> 2) + 4 * kh;
                int gi = rowBase + mi * 32 + rowf;
                float nqi = ((const float*)&nq4[mi][reg >> 2])[reg & 3];
#pragma unroll
                for (int ni = 0; ni < 2; ++ni) {
                    int gj = colBase + ni * 32 + ln31;
                    float arg = fmaf(accf[mi][ni][reg], 2.f * C2, nqi + nqj[ni]);
                    float e = __builtin_exp2f(fminf(arg, 0.f));
                    local += (gi < gj) ? e : 0.f;
                }
            }
        }
    }

#pragma unroll
    for (int off = 32; off; off >>= 1) local += __shfl_down(local, off);
    if (lane == 0) wsum[wave] = local;
    __syncthreads();
    if (tid == 0) part[blockIdx.x] = wsum[0] + wsum[1] + wsum[2] + wsum[3];  // plain store
}

// Single small block: sum the 2080 partials, take the log. The kernel
// boundary before this launch is the only coherence fence in the pipeline.
__global__ __launch_bounds__(256) void reduce_kernel(const float* __restrict__ part,
                                                     float* __restrict__ out) {
    int tid = threadIdx.x;
    int wave = tid >> 6, lane = tid & 63;
    float s = 0.f;
    for (int i = tid; i < NBLK; i += 256) s += part[i];
#pragma unroll
    for (int off = 32; off; off >>= 1) s += __shfl_down(s, off);
    __shared__ float w[4];
    if (lane == 0) w[wave] = s;
    __syncthreads();
    if (tid == 0) {
        float total = 2.f * (w[0] + w[1] + w[2] + w[3]);
        out[0] = logf(total / ((float)NROWS * (float)(NROWS - 1)));
    }
}

extern "C" void kernel_launch(void* const* d_in, const int* in_sizes, int n_in,
                              void* d_out, int out_size, void* d_ws, size_t ws_size,
                              hipStream_t stream) {
    const float* z = (const float*)d_in[0];
    float* out = (float*)d_out;
    unsigned char* zb4 = (unsigned char*)d_ws;                    // 2 MB fp4, operand order
    float* nq = (float*)((char*)d_ws + (size_t)NROWS * KDIM / 2); // 32 KB
    float* part = nq + NROWS;                                     // 2080 floats

    prep_kernel<<<NROWS / 4, 256, 0, stream>>>(z, zb4, nq);
    gram_kernel<<<NBLK, 256, 0, stream>>>(zb4, nq, part);
    reduce_kernel<<<1, 256, 0, stream>>>(part, out);
}

// Round 10
// 84.908 us; speedup vs baseline: 1.0248x; 1.0248x over previous
//
#include <hip/hip_runtime.h>

#define NROWS 8192
#define KDIM  512
#define NT    64                 // 8192/128 tiles per dim
#define NBLK  (NT*(NT+1)/2)      // upper-triangle tile pairs = 2080
#define SCL1  0x7F7F7F7F         // E8M0 scale bytes = 2^0 = 1.0
#define STRIP4 8192              // 32 rows x 512 k x 0.5 B per strip
#define C2    0.0144269504f      // log2(e)/100

typedef __attribute__((ext_vector_type(16))) float f32x16;
typedef __attribute__((ext_vector_type(4))) int i32x4;
typedef __attribute__((ext_vector_type(8))) int i32x8;

__device__ __forceinline__ i32x8 mk_op4(i32x4 lo) {
    i32x8 r;
    r[0] = lo[0]; r[1] = lo[1]; r[2] = lo[2]; r[3] = lo[3];
    r[4] = 0; r[5] = 0; r[6] = 0; r[7] = 0;   // fp4 uses only first 4 dwords
    return r;
}

// nearest e2m1 (scale 1.0) code for |x|: {0,0.5,1,1.5,2,3,4,6}
__device__ __forceinline__ int fp4_code(float x) {
    float v = fabsf(x);
    int c = v < 0.25f ? 0 : v < 0.75f ? 1 : v < 1.25f ? 2 : v < 1.75f ? 3
          : v < 2.5f  ? 4 : v < 3.5f  ? 5 : v < 5.0f  ? 6 : 7;
    return c | (x < 0.f ? 8 : 0);
}

// z (fp32) -> fp4 e2m1 in MFMA-operand order (bitwise identical zb4/nq to all
// prior rounds). nq[i] = -log2e/100 * ||z_i||^2 (exact fp32).
__global__ __launch_bounds__(256) void prep_kernel(const float* __restrict__ z,
                                                   unsigned char* __restrict__ zb4,
                                                   float* __restrict__ nq) {
    int wave = threadIdx.x >> 6, lane = threadIdx.x & 63;
    int row = blockIdx.x * 4 + wave;
    const float* zr = z + (size_t)row * KDIM + lane * 8;
    float4 v0 = *(const float4*)zr;
    float4 v1 = *(const float4*)(zr + 4);
    float vals[8] = {v0.x, v0.y, v0.z, v0.w, v1.x, v1.y, v1.z, v1.w};
    float s = 0.f;
    unsigned int pk = 0u;
#pragma unroll
    for (int i = 0; i < 8; ++i) {
        s += vals[i] * vals[i];
        pk |= (unsigned int)fp4_code(vals[i]) << (4 * i);   // nibble i = k0+i
    }
    int strip = row >> 5, lr = row & 31;
    size_t addr = (size_t)strip * STRIP4 + (lane >> 3) * 1024 +
                  ((lane >> 2) & 1) * 512 + lr * 16 + (lane & 3) * 4;
    *(unsigned int*)(zb4 + addr) = pk;
#pragma unroll
    for (int off = 32; off; off >>= 1) s += __shfl_down(s, off);
    if (lane == 0) nq[row] = -C2 * s;
}

// 128x128 Gram tile per block, 64x64 per wave (2x2 32x32x64 MX-fp4 MFMA).
// ROUND 10: full-K operand hoist at (256,2). Ledger: L2-latency batching (r5),
// occupancy (r7), MFMA:load ratio + L2 traffic (r8), L1/TA lines + LDS pipe
// (r9) — all null; gram pinned at ~27 us. The shared invariant across all:
// compiler keeps VGPR_Count ~52 (measured r2) = only ~3 loads in flight per
// wave -> every k-step's MFMA eats an exposed L2 round trip. Fix the actual
// knob: (256,2) raises the per-lane cap to 256; explicit fully-unrolled
// load arrays (4 strips x 8 slices = 128 VGPRs) hoist the ENTIRE operand
// stream before the first MFMA; the 32-MFMA chain then runs with one drain.
// Budget 128 + 64 acc (unified file) + ~40 temps ~= 232 <= 256: no spill
// (r6's disaster was a 128-cap clamp at (256,4), not this). 2 blocks/CU
// cover epilogue/launch seams. Load order is sum-irrelevant; per-acc MFMA
// order unchanged (ks=0..7, rotated slices) -> bitwise-identical result.
// No barriers, plain store, separate reduce (r1-r4: per-block agent-scope
// fences cost >= 15 us; kernel boundary = free fence).
__global__ __launch_bounds__(256, 2) void gram_kernel(const unsigned char* __restrict__ zb4,
                                                      const float* __restrict__ nq,
                                                      float* __restrict__ part) {
    __shared__ float wsum[4];

    int tid = threadIdx.x;
    int wave = tid >> 6, lane = tid & 63;
    int ln31 = lane & 31, kh = lane >> 5;
    int wm = wave >> 1, wn = wave & 1;

    // linear block id -> (bi, bj), bi <= bj : closed form + fixup (round 5)
    int x = blockIdx.x;
    float sqv = __builtin_sqrtf(16641.0f - 8.0f * (float)x);   // (2*NT+1)^2
    int bi = (int)((129.0f - sqv) * 0.5f);
    while ((bi + 1) * NT - ((bi + 1) * bi >> 1) <= x) ++bi;
    while (bi * NT - (bi * (bi - 1) >> 1) > x) --bi;
    int rem = x - (bi * NT - (bi * (bi - 1) >> 1));
    int bj = bi + rem;
    int rot = blockIdx.x & 7;

    int laneOff = kh * 512 + ln31 * 16;
    const unsigned char* pA0 = zb4 + (size_t)(bi * 4 + wm * 2) * STRIP4 + laneOff;
    const unsigned char* pA1 = pA0 + STRIP4;
    const unsigned char* pB0 = zb4 + (size_t)(bj * 4 + wn * 2) * STRIP4 + laneOff;
    const unsigned char* pB1 = pB0 + STRIP4;

    // ---- hoist the ENTIRE operand stream: 32 x 16B loads, 128 VGPRs ----
    i32x4 lA0[8], lA1[8], lB0[8], lB1[8];
#pragma unroll
    for (int ks = 0; ks < 8; ++ks) {
        int off = ((ks + rot) & 7) * 1024;   // rotated k-slice
        lA0[ks] = *(const i32x4*)(pA0 + off);
        lA1[ks] = *(const i32x4*)(pA1 + off);
        lB0[ks] = *(const i32x4*)(pB0 + off);
        lB1[ks] = *(const i32x4*)(pB1 + off);
    }

    // ---- epilogue nq operands (independent; issue alongside the hoist) ----
    int rowBase = bi * 128 + wm * 64;
    int colBase = bj * 128 + wn * 64;
    float nqj[2] = { nq[colBase + ln31], nq[colBase + 32 + ln31] };
    float4 nq4[2][4];
#pragma unroll
    for (int mi = 0; mi < 2; ++mi)
#pragma unroll
        for (int g = 0; g < 4; ++g)
            nq4[mi][g] = *(const float4*)(nq + rowBase + mi * 32 + 4 * kh + 8 * g);

    f32x16 accf[2][2];
#pragma unroll
    for (int mi = 0; mi < 2; ++mi)
#pragma unroll
        for (int ni = 0; ni < 2; ++ni)
#pragma unroll
            for (int r = 0; r < 16; ++r) accf[mi][ni][r] = 0.f;

    // ---- 32-MFMA chain; operands already resident in registers ----
#pragma unroll
    for (int ks = 0; ks < 8; ++ks) {
        i32x8 a0 = mk_op4(lA0[ks]);
        i32x8 a1 = mk_op4(lA1[ks]);
        i32x8 b0 = mk_op4(lB0[ks]);
        i32x8 b1 = mk_op4(lB1[ks]);
        // cbsz=4 (A=fp4), blgp=4 (B=fp4), scales = 1.0
        accf[0][0] = __builtin_amdgcn_mfma_scale_f32_32x32x64_f8f6f4(a0, b0, accf[0][0], 4, 4, 0, SCL1, 0, SCL1);
        accf[0][1] = __builtin_amdgcn_mfma_scale_f32_32x32x64_f8f6f4(a0, b1, accf[0][1], 4, 4, 0, SCL1, 0, SCL1);
        accf[1][0] = __builtin_amdgcn_mfma_scale_f32_32x32x64_f8f6f4(a1, b0, accf[1][0], 4, 4, 0, SCL1, 0, SCL1);
        accf[1][1] = __builtin_amdgcn_mfma_scale_f32_32x32x64_f8f6f4(a1, b1, accf[1][1], 4, 4, 0, SCL1, 0, SCL1);
    }

    // ---- fused epilogue: exp2( min( s*2C2 + nq_i + nq_j, 0 ) ) ----
    float local = 0.f;
    if (bi != bj) {
#pragma unroll
        for (int mi = 0; mi < 2; ++mi) {
#pragma unroll
            for (int reg = 0; reg < 16; ++reg) {
                float nqi = ((const float*)&nq4[mi][reg >> 2])[reg & 3];
#pragma unroll
                for (int ni = 0; ni < 2; ++ni) {
                    float arg = fmaf(accf[mi][ni][reg], 2.f * C2, nqi + nqj[ni]);
                    local += __builtin_exp2f(fminf(arg, 0.f));
                }
            }
        }
    } else {
#pragma unroll
        for (int mi = 0; mi < 2; ++mi) {
#pragma unroll
            for (int reg = 0; reg < 16; ++reg) {
                int rowf = (reg & 3) + 8 * (reg >> 2) + 4 * kh;
                int gi = rowBase + mi * 32 + rowf;
                float nqi = ((const float*)&nq4[mi][reg >> 2])[reg & 3];
#pragma unroll
                for (int ni = 0; ni < 2; ++ni) {
                    int gj = colBase + ni * 32 + ln31;
                    float arg = fmaf(accf[mi][ni][reg], 2.f * C2, nqi + nqj[ni]);
                    float e = __builtin_exp2f(fminf(arg, 0.f));
                    local += (gi < gj) ? e : 0.f;
                }
            }
        }
    }

#pragma unroll
    for (int off = 32; off; off >>= 1) local += __shfl_down(local, off);
    if (lane == 0) wsum[wave] = local;
    __syncthreads();
    if (tid == 0) part[blockIdx.x] = wsum[0] + wsum[1] + wsum[2] + wsum[3];  // plain store
}

// Single small block: sum the 2080 partials, take the log. The kernel
// boundary before this launch is the only coherence fence in the pipeline.
__global__ __launch_bounds__(256) void reduce_kernel(const float* __restrict__ part,
                                                     float* __restrict__ out) {
    int tid = threadIdx.x;
    int wave = tid >> 6, lane = tid & 63;
    float s = 0.f;
    for (int i = tid; i < NBLK; i += 256) s += part[i];
#pragma unroll
    for (int off = 32; off; off >>= 1) s += __shfl_down(s, off);
    __shared__ float w[4];
    if (lane == 0) w[wave] = s;
    __syncthreads();
    if (tid == 0) {
        float total = 2.f * (w[0] + w[1] + w[2] + w[3]);
        out[0] = logf(total / ((float)NROWS * (float)(NROWS - 1)));
    }
}

extern "C" void kernel_launch(void* const* d_in, const int* in_sizes, int n_in,
                              void* d_out, int out_size, void* d_ws, size_t ws_size,
                              hipStream_t stream) {
    const float* z = (const float*)d_in[0];
    float* out = (float*)d_out;
    unsigned char* zb4 = (unsigned char*)d_ws;                    // 2 MB fp4, operand order
    float* nq = (float*)((char*)d_ws + (size_t)NROWS * KDIM / 2); // 32 KB
    float* part = nq + NROWS;                                     // 2080 floats

    prep_kernel<<<NROWS / 4, 256, 0, stream>>>(z, zb4, nq);
    gram_kernel<<<NBLK, 256, 0, stream>>>(zb4, nq, part);
    reduce_kernel<<<1, 256, 0, stream>>>(part, out);
}